// Round 20
// baseline (348.373 us; speedup 1.0000x reference)
//
#include <hip/hip_runtime.h>

// GIN encoder: N=100k, E=3.2M, G=512, H=64, L=3.
// Round 20 (R19 = 345us base):
//  - gin_layer gather unroll 4->8 (8 outstanding loads/thread; VALU 55% has
//    slack to cover unpack while more loads fill the memory shadow).
//  - bn_pool_out vectorized: uint4 reads, 8 cols/thread x 32 rows parallel.
//  - prep_weights folded into scatter_sort grid (block nblk) -> 1 less launch.
// Rest identical to R19 (wave-scan CSR build, fused gin_layer, bn_reduce v2).

#define NBMAX 1024
#define CAP 4608
#define CHUNK 8192
#define NBLK_MAX 512
#define MSTR 72   // LDS row stride in shorts (9 uint4, bank-staggered)

typedef __attribute__((ext_vector_type(8))) short bf16x8;
typedef __attribute__((ext_vector_type(4))) float f32x4;

static __device__ __forceinline__ bf16x8 as_bf16x8(uint4 u) {
    union { uint4 a; bf16x8 b; } x; x.a = u; return x.b;
}
static __device__ __forceinline__ unsigned short bf16r(float v) {
    unsigned u = __float_as_uint(v);
    return (unsigned short)((u + 0x7FFFu + ((u >> 16) & 1u)) >> 16);
}
static __device__ __forceinline__ unsigned bf16pack2(float a, float b) {
    return (unsigned)bf16r(a) | ((unsigned)bf16r(b) << 16);
}

// ---- scatter_sort + fused weight prep (block == nblk does weights) ----
__global__ __launch_bounds__(512) void scatter_sort(
    const int* __restrict__ src, const int* __restrict__ dst,
    int* __restrict__ bucketed2, int* __restrict__ offsTab, int E, int nblk,
    const float* __restrict__ w1_0, const float* __restrict__ w1_r,
    const float* __restrict__ w2, unsigned short* __restrict__ w1T0,
    unsigned short* __restrict__ w1T, unsigned short* __restrict__ w2T) {
    int t = threadIdx.x, blk = blockIdx.x;
    if (blk >= nblk) {
        // weight prep: bf16, transposed to [col][k]
        for (int i = t; i < 64 * 32; i += 512) {
            int c = i >> 5, k = i & 31;
            w1T0[i] = bf16r(k < 3 ? w1_0[k * 64 + c] : 0.f);
        }
        for (int i = t; i < 2 * 64 * 64; i += 512) {
            int l = i >> 12, r = i & 4095, c = r >> 6, k = r & 63;
            w1T[i] = bf16r(w1_r[l * 4096 + k * 64 + c]);
        }
        for (int i = t; i < 3 * 64 * 64; i += 512) {
            int l = i >> 12, r = i & 4095, c = r >> 6, k = r & 63;
            w2T[i] = bf16r(w2[l * 4096 + k * 64 + c]);
        }
        return;
    }
    __shared__ int hist[NBMAX];
    __shared__ int offs[NBMAX];
    __shared__ int stage[CHUNK];
    __shared__ int wsum8[8];
    int e0 = blk * CHUNK, e1 = min(e0 + CHUNK, E);
    int len = e1 - e0;
    hist[t] = 0; hist[t + 512] = 0;
    __syncthreads();
    for (int e = e0 + t; e < e1; e += 512) atomicAdd(&hist[dst[e] >> 7], 1);
    __syncthreads();
    int h0 = hist[2 * t], h1 = hist[2 * t + 1];
    int pair = h0 + h1;
    int lane = t & 63;
    int incl = pair;
#pragma unroll
    for (int d = 1; d < 64; d <<= 1) {
        int up = __shfl_up(incl, d);
        if (lane >= d) incl += up;
    }
    if (lane == 63) wsum8[t >> 6] = incl;
    __syncthreads();
    int wid = t >> 6, wpre = 0;
    for (int i = 0; i < wid; i++) wpre += wsum8[i];
    int exclP = wpre + incl - pair;
    offs[2 * t] = exclP;
    offs[2 * t + 1] = exclP + h0;
    hist[2 * t] = 0; hist[2 * t + 1] = 0;
    __syncthreads();
    offsTab[blk * 1025 + t] = offs[t];
    offsTab[blk * 1025 + t + 512] = offs[t + 512];
    if (t == 0) offsTab[blk * 1025 + 1024] = len;
    for (int e = e0 + t; e < e1; e += 512) {
        int d = dst[e];
        int bk = d >> 7;
        int r = offs[bk] + atomicAdd(&hist[bk], 1);
        stage[r] = src[e] | ((d & 127) << 20);
    }
    __syncthreads();
    for (int j = t; j < len; j += 512) bucketed2[e0 + j] = stage[j];
}

// ---- bucket_csr v4: wave scans; binsearch run-gather; src-block then row
// counting sorts -> CSR with ~src-ascending rows ----
__global__ __launch_bounds__(256) void bucket_csr(
    const int* __restrict__ bucketed2, const int* __restrict__ offsTab,
    int* __restrict__ csrOut, int* __restrict__ rowstart, int* __restrict__ rowend,
    int N, int nblk) {
    __shared__ int ein[CAP];
    __shared__ int emid[CAP];
    __shared__ int runs[NBLK_MAX];
    __shared__ int rbeg[NBLK_MAX];
    __shared__ int hist[128];
    __shared__ int base[129];
    __shared__ int wsum4[4];
    __shared__ int wtot2[2];
    int b = blockIdx.x, t = threadIdx.x, node0 = b << 7;
    for (int r = t; r < NBLK_MAX; r += 256) {
        int l = 0, g0 = 0;
        if (r < nblk) {
            int beg = offsTab[r * 1025 + b];
            int end = offsTab[r * 1025 + b + 1];
            l = end - beg;
            g0 = r * CHUNK + beg;
        }
        runs[r] = l;
        rbeg[r] = g0;
    }
    __syncthreads();
    {
        int l0 = runs[2 * t], l1 = runs[2 * t + 1];
        int pair = l0 + l1;
        int lane = t & 63;
        int incl = pair;
#pragma unroll
        for (int d = 1; d < 64; d <<= 1) {
            int up = __shfl_up(incl, d);
            if (lane >= d) incl += up;
        }
        if (lane == 63) wsum4[t >> 6] = incl;
        __syncthreads();
        int wid = t >> 6, wpre = 0;
        for (int i = 0; i < wid; i++) wpre += wsum4[i];
        int exclP = wpre + incl - pair;
        runs[2 * t] = exclP + l0;
        runs[2 * t + 1] = exclP + l0 + l1;
    }
    __syncthreads();
    int cnt = min(runs[NBLK_MAX - 1], CAP);
    for (int j = t; j < cnt; j += 256) {
        int lo = 0, hi = nblk - 1;
        while (lo < hi) {
            int m = (lo + hi) >> 1;
            if (runs[m] > j) hi = m; else lo = m + 1;
        }
        int st = lo ? runs[lo - 1] : 0;
        ein[j] = bucketed2[rbeg[lo] + (j - st)];
    }
    // pass 1: group by src block (src>>10)
    if (t < 128) hist[t] = 0;
    __syncthreads();
    for (int j = t; j < cnt; j += 256) atomicAdd(&hist[(ein[j] & 0xFFFFF) >> 10], 1);
    __syncthreads();
    {
        int lane = t & 63;
        int hv = (t < 128) ? hist[t] : 0;
        int incl = hv;
#pragma unroll
        for (int d = 1; d < 64; d <<= 1) {
            int up = __shfl_up(incl, d);
            if (lane >= d) incl += up;
        }
        if (t < 128 && lane == 63) wtot2[t >> 6] = incl;
        __syncthreads();
        if (t >= 64 && t < 128) incl += wtot2[0];
        if (t < 128) { base[t + 1] = incl; hist[t] = 0; }
        if (t == 0) base[0] = 0;
    }
    __syncthreads();
    for (int j = t; j < cnt; j += 256) {
        int p = ein[j];
        int sb = (p & 0xFFFFF) >> 10;
        int pos = base[sb] + atomicAdd(&hist[sb], 1);
        emid[pos] = p;
    }
    __syncthreads();
    // pass 2: counting sort by row
    if (t < 128) hist[t] = 0;
    __syncthreads();
    for (int j = t; j < cnt; j += 256) atomicAdd(&hist[emid[j] >> 20], 1);
    __syncthreads();
    {
        int lane = t & 63;
        int hv = (t < 128) ? hist[t] : 0;
        int incl = hv;
#pragma unroll
        for (int d = 1; d < 64; d <<= 1) {
            int up = __shfl_up(incl, d);
            if (lane >= d) incl += up;
        }
        if (t < 128 && lane == 63) wtot2[t >> 6] = incl;
        __syncthreads();
        if (t >= 64 && t < 128) incl += wtot2[0];
        if (t < 128) { base[t + 1] = incl; hist[t] = 0; }
        if (t == 0) base[0] = 0;
    }
    __syncthreads();
    if (t < 128) {
        int n = node0 + t;
        if (n < N) {
            rowstart[n] = b * CAP + base[t];
            rowend[n] = b * CAP + base[t + 1];
        }
    }
    __syncthreads();
    for (int j = t; j < cnt; j += 256) {
        int p = emid[j];
        int local = p >> 20;
        int pos = base[local] + atomicAdd(&hist[local], 1);
        ein[pos] = p & 0xFFFFF;
    }
    __syncthreads();
    for (int j = t; j < cnt; j += 256) csrOut[b * CAP + j] = ein[j];
}

// bf16x2-packed accumulate of relu(v*sc+sh)
__device__ __forceinline__ void accum_bf16(const uint4 u,
                                           const float4 scA, const float4 scB,
                                           const float4 shA, const float4 shB,
                                           float* __restrict__ a) {
    a[0] += fmaxf(__uint_as_float(u.x << 16) * scA.x + shA.x, 0.f);
    a[1] += fmaxf(__uint_as_float(u.x & 0xFFFF0000u) * scA.y + shA.y, 0.f);
    a[2] += fmaxf(__uint_as_float(u.y << 16) * scA.z + shA.z, 0.f);
    a[3] += fmaxf(__uint_as_float(u.y & 0xFFFF0000u) * scA.w + shA.w, 0.f);
    a[4] += fmaxf(__uint_as_float(u.z << 16) * scB.x + shB.x, 0.f);
    a[5] += fmaxf(__uint_as_float(u.z & 0xFFFF0000u) * scB.y + shB.y, 0.f);
    a[6] += fmaxf(__uint_as_float(u.w << 16) * scB.z + shB.z, 0.f);
    a[7] += fmaxf(__uint_as_float(u.w & 0xFFFF0000u) * scB.w + shB.w, 0.f);
}

// ---- fused GIN layer v4.2: 256 threads, 32-node tile (grid 3125).
// L1/L2 gather: 8 lanes/node, unroll 8. L0: 8 row-segments/node. ----
template <bool L0>
__global__ __launch_bounds__(256) void gin_layer(
    const void* __restrict__ actInRaw,
    const int* __restrict__ rowstart, const int* __restrict__ rowend,
    const int* __restrict__ csr,
    const float* __restrict__ bnsumPrev, const float* __restrict__ bnsqPrev,
    const float* __restrict__ gammaPrev, const float* __restrict__ betaPrev,
    const uint4* __restrict__ w1Tu, const float* __restrict__ b1,
    const uint4* __restrict__ w2Tu, const float* __restrict__ b2,
    uint4* __restrict__ houtU4,
    float* __restrict__ partS, float* __restrict__ partQ, int N) {
    __shared__ __align__(16) unsigned short acts[32 * MSTR];  // 4.5KB
    __shared__ __align__(16) unsigned short mids[32 * MSTR];  // 4.5KB
    __shared__ float red[8][64];                              // 2KB
    __shared__ float scs[64], shs[64];
    int t = threadIdx.x;
    int tileBase = blockIdx.x * 32;
    uint4* actsU4 = (uint4*)acts;
    const uint4* midU4 = (const uint4*)mids;
    const uint4 z4 = make_uint4(0, 0, 0, 0);

    if (!L0) {
        if (t < 64) {
            float mu = bnsumPrev[t] / (float)N;
            float var = bnsqPrev[t] / (float)N - mu * mu;
            float s = gammaPrev[t] * rsqrtf(var + 1e-5f);
            scs[t] = s;
            shs[t] = betaPrev[t] - mu * s;
        }
        __syncthreads();
    }

    // ---- gather phase ----
    if (L0) {
        const float* x = (const float*)actInRaw;
        int ni = t & 31, seg = t >> 5;
        int n = tileBase + ni;
        float s0 = 0.f, s1 = 0.f, s2 = 0.f;
        if (n < N) {
            int srow = rowstart[n], erow = rowend[n];
            for (int j = srow + seg; j < erow; j += 8) {
                int nb = csr[j];
                s0 += x[nb * 3]; s1 += x[nb * 3 + 1]; s2 += x[nb * 3 + 2];
            }
            if (seg == 0) { s0 += x[n * 3]; s1 += x[n * 3 + 1]; s2 += x[n * 3 + 2]; }
        }
        float* stg = (float*)mids;
        stg[seg * 96 + ni * 3 + 0] = s0;
        stg[seg * 96 + ni * 3 + 1] = s1;
        stg[seg * 96 + ni * 3 + 2] = s2;
        __syncthreads();
        if (t < 32) {
            float a0 = 0.f, a1 = 0.f, a2 = 0.f;
#pragma unroll
            for (int g2 = 0; g2 < 8; g2++) {
                a0 += stg[g2 * 96 + t * 3 + 0];
                a1 += stg[g2 * 96 + t * 3 + 1];
                a2 += stg[g2 * 96 + t * 3 + 2];
            }
            actsU4[t * 9] = make_uint4(bf16pack2(a0, a1), bf16pack2(a2, 0.f), 0u, 0u);
        }
    } else {
        const uint4* hr = (const uint4*)actInRaw;
        int ni = t >> 3, l = t & 7;
        int n = tileBase + ni;
        int c0i = l * 8;
        float4 scA = *(const float4*)&scs[c0i], scB = *(const float4*)&scs[c0i + 4];
        float4 shA = *(const float4*)&shs[c0i], shB = *(const float4*)&shs[c0i + 4];
        float A[8] = {0,0,0,0,0,0,0,0};
        float B[8] = {0,0,0,0,0,0,0,0};
        if (n < N) {
            accum_bf16(hr[(size_t)n * 8 + l], scA, scB, shA, shB, A);  // self
            int s = rowstart[n], e = rowend[n];
            int j = s;
            for (; j + 7 < e; j += 8) {
                int i0 = csr[j], i1 = csr[j + 1], i2 = csr[j + 2], i3 = csr[j + 3];
                int i4 = csr[j + 4], i5 = csr[j + 5], i6 = csr[j + 6], i7 = csr[j + 7];
                uint4 w0 = hr[(size_t)i0 * 8 + l];
                uint4 w1 = hr[(size_t)i1 * 8 + l];
                uint4 w2 = hr[(size_t)i2 * 8 + l];
                uint4 w3 = hr[(size_t)i3 * 8 + l];
                uint4 w4 = hr[(size_t)i4 * 8 + l];
                uint4 w5 = hr[(size_t)i5 * 8 + l];
                uint4 w6 = hr[(size_t)i6 * 8 + l];
                uint4 w7 = hr[(size_t)i7 * 8 + l];
                accum_bf16(w0, scA, scB, shA, shB, A);
                accum_bf16(w1, scA, scB, shA, shB, B);
                accum_bf16(w2, scA, scB, shA, shB, A);
                accum_bf16(w3, scA, scB, shA, shB, B);
                accum_bf16(w4, scA, scB, shA, shB, A);
                accum_bf16(w5, scA, scB, shA, shB, B);
                accum_bf16(w6, scA, scB, shA, shB, A);
                accum_bf16(w7, scA, scB, shA, shB, B);
            }
            for (; j + 3 < e; j += 4) {
                int i0 = csr[j], i1 = csr[j + 1], i2 = csr[j + 2], i3 = csr[j + 3];
                uint4 w0 = hr[(size_t)i0 * 8 + l];
                uint4 w1 = hr[(size_t)i1 * 8 + l];
                uint4 w2 = hr[(size_t)i2 * 8 + l];
                uint4 w3 = hr[(size_t)i3 * 8 + l];
                accum_bf16(w0, scA, scB, shA, shB, A);
                accum_bf16(w1, scA, scB, shA, shB, B);
                accum_bf16(w2, scA, scB, shA, shB, A);
                accum_bf16(w3, scA, scB, shA, shB, B);
            }
            for (; j < e; j++) {
                uint4 w = hr[(size_t)csr[j] * 8 + l];
                accum_bf16(w, scA, scB, shA, shB, A);
            }
        }
        uint4 o;
        o.x = bf16pack2(A[0] + B[0], A[1] + B[1]);
        o.y = bf16pack2(A[2] + B[2], A[3] + B[3]);
        o.z = bf16pack2(A[4] + B[4], A[5] + B[5]);
        o.w = bf16pack2(A[6] + B[6], A[7] + B[7]);
        actsU4[ni * 9 + l] = o;
    }

    // ---- MFMA phase: wave w -> col-group w*16, row-groups 0..1 ----
    int w = t >> 6, l64 = t & 63, m16 = l64 & 15, q = l64 >> 4;
    int col = w * 16 + m16;
    bf16x8 w1f0, w1f1, w2f0, w2f1;
    float bias1 = b1[col], bias2 = b2[col];
    if (L0) {
        w1f0 = as_bf16x8(w1Tu[col * 4 + q]);
    } else {
        w1f0 = as_bf16x8(w1Tu[col * 8 + q]);
        w1f1 = as_bf16x8(w1Tu[col * 8 + 4 + q]);
    }
    w2f0 = as_bf16x8(w2Tu[col * 8 + q]);
    w2f1 = as_bf16x8(w2Tu[col * 8 + 4 + q]);
    __syncthreads();  // S1: acts ready
#pragma unroll
    for (int rg = 0; rg < 2; rg++) {
        int rloc = rg * 16 + m16;
        bf16x8 a0 = as_bf16x8(L0 ? (q == 0 ? actsU4[rloc * 9] : z4)
                                 : actsU4[rloc * 9 + q]);
        f32x4 acc = {bias1, bias1, bias1, bias1};
        if (L0) {
            acc = __builtin_amdgcn_mfma_f32_16x16x32_bf16(a0, w1f0, acc, 0, 0, 0);
        } else {
            bf16x8 a1 = as_bf16x8(actsU4[rloc * 9 + 4 + q]);
            acc = __builtin_amdgcn_mfma_f32_16x16x32_bf16(a0, w1f0, acc, 0, 0, 0);
            acc = __builtin_amdgcn_mfma_f32_16x16x32_bf16(a1, w1f1, acc, 0, 0, 0);
        }
#pragma unroll
        for (int r = 0; r < 4; r++) {
            int row = rg * 16 + q * 4 + r;
            mids[row * MSTR + col] = bf16r(fmaxf(acc[r], 0.f));
        }
    }
    __syncthreads();  // S2: mids ready
    f32x4 accs[2];
#pragma unroll
    for (int rg = 0; rg < 2; rg++) {
        int rloc = rg * 16 + m16;
        bf16x8 a20 = as_bf16x8(midU4[rloc * 9 + q]);
        bf16x8 a21 = as_bf16x8(midU4[rloc * 9 + 4 + q]);
        f32x4 acc = {bias2, bias2, bias2, bias2};
        acc = __builtin_amdgcn_mfma_f32_16x16x32_bf16(a20, w2f0, acc, 0, 0, 0);
        acc = __builtin_amdgcn_mfma_f32_16x16x32_bf16(a21, w2f1, acc, 0, 0, 0);
        accs[rg] = acc;
    }
    float sA = 0.f, sB = 0.f, qA = 0.f, qB = 0.f;
#pragma unroll
    for (int rg = 0; rg < 2; rg++) {
#pragma unroll
        for (int r = 0; r < 4; r++) {
            int row = rg * 16 + q * 4 + r;
            float v = accs[rg][r];
            if (tileBase + row < N) {
                if (rg == 0) { sA += v; qA += v * v; } else { sB += v; qB += v * v; }
            }
            acts[row * MSTR + col] = bf16r(v);
        }
    }
    __syncthreads();  // S3: output staged
    {
        int row = t >> 3, qo = t & 7;
        int gr = tileBase + row;
        if (gr < N) houtU4[(size_t)gr * 8 + qo] = actsU4[row * 9 + qo];
    }
    red[q][col] = sA;
    red[4 + q][col] = sB;
    __syncthreads();
    if (t < 64) {
        float S = 0.f;
        for (int i = 0; i < 8; i++) S += red[i][t];
        partS[blockIdx.x * 64 + t] = S;
    }
    __syncthreads();
    red[q][col] = qA;
    red[4 + q][col] = qB;
    __syncthreads();
    if (t < 64) {
        float S = 0.f;
        for (int i = 0; i < 8; i++) S += red[i][t];
        partQ[blockIdx.x * 64 + t] = S;
    }
}

// ---- bn_reduce v2: 64 blocks, block b reduces column b over nParts ----
__global__ __launch_bounds__(256) void bn_reduce(
    const float* __restrict__ partS, const float* __restrict__ partQ,
    float* __restrict__ bnsum, float* __restrict__ bnsq, int nParts) {
    __shared__ float rs[256], rq[256];
    int b = blockIdx.x, t = threadIdx.x;
    float S = 0.f, Q = 0.f;
    for (int p = t; p < nParts; p += 256) {
        S += partS[p * 64 + b];
        Q += partQ[p * 64 + b];
    }
    rs[t] = S; rq[t] = Q;
    __syncthreads();
    for (int off = 128; off > 0; off >>= 1) {
        if (t < off) { rs[t] += rs[t + off]; rq[t] += rq[t + off]; }
        __syncthreads();
    }
    if (t == 0) { bnsum[b] = rs[0]; bnsq[b] = rq[0]; }
}

// ---- BN apply + mean-pool + output matmul; vectorized uint4 reads ----
__device__ __forceinline__ int lowb(const int* __restrict__ a, int n, int v) {
    int lo = 0, hi = n;
    while (lo < hi) {
        int m = (lo + hi) >> 1;
        if (a[m] < v) lo = m + 1; else hi = m;
    }
    return lo;
}

__global__ __launch_bounds__(256) void bn_pool_out(
    const uint4* __restrict__ hr, const int* __restrict__ batch,
    const float* __restrict__ bnsum, const float* __restrict__ bnsq,
    const float* __restrict__ gamma, const float* __restrict__ beta,
    const float* __restrict__ wout, const float* __restrict__ bout,
    float* __restrict__ out, int N) {
    __shared__ float sc[64], sh[64];
    __shared__ float part[32][64];
    __shared__ float gr[64];
    __shared__ int range[2];
    int g = blockIdx.x, t = threadIdx.x;
    if (t < 64) {
        float mu = bnsum[t] / (float)N;
        float var = bnsq[t] / (float)N - mu * mu;
        float s = gamma[t] * rsqrtf(var + 1e-5f);
        sc[t] = s;
        sh[t] = beta[t] - mu * s;
    }
    if (t == 64) range[0] = lowb(batch, N, g);
    if (t == 65) range[1] = lowb(batch, N, g + 1);
    __syncthreads();
    int s0 = range[0], s1 = range[1];
    int o = t & 7, ro = t >> 3;       // col-octet, row slice (32 rows parallel)
    int c0 = o * 8;
    float4 scA = *(const float4*)&sc[c0], scB = *(const float4*)&sc[c0 + 4];
    float4 shA = *(const float4*)&sh[c0], shB = *(const float4*)&sh[c0 + 4];
    float A[8] = {0,0,0,0,0,0,0,0};
    for (int n = s0 + ro; n < s1; n += 32) {
        uint4 u = hr[(size_t)n * 8 + o];
        accum_bf16(u, scA, scB, shA, shB, A);
    }
#pragma unroll
    for (int k = 0; k < 8; k++) part[ro][c0 + k] = A[k];
    __syncthreads();
    if (t < 64) {
        float S = 0.f;
        for (int i = 0; i < 32; i++) S += part[i][t];
        float c = (float)(s1 - s0);
        gr[t] = (c > 0.f) ? S / c : 0.f;
    }
    __syncthreads();
    if (t < 64) {
        float a = bout[t];
        for (int f = 0; f < 64; f++) a += gr[f] * wout[f * 64 + t];
        out[g * 64 + t] = a;
    }
}

extern "C" void kernel_launch(void* const* d_in, const int* in_sizes, int n_in,
                              void* d_out, int out_size, void* d_ws, size_t ws_size,
                              hipStream_t stream) {
    const float* x     = (const float*)d_in[0];
    const int*   ei    = (const int*)d_in[1];
    const int*   batch = (const int*)d_in[2];
    const float* w1_0  = (const float*)d_in[3];
    const float* w1_r  = (const float*)d_in[4];
    const float* b1    = (const float*)d_in[5];
    const float* w2    = (const float*)d_in[6];
    const float* b2    = (const float*)d_in[7];
    const float* gamma = (const float*)d_in[8];
    const float* beta  = (const float*)d_in[9];
    const float* wout  = (const float*)d_in[10];
    const float* bout  = (const float*)d_in[11];
    float* out = (float*)d_out;

    const int N = in_sizes[2];               // 100000
    const int E = in_sizes[1] / 2;           // 3200000
    const int NB = (N + 127) >> 7;           // 782 buckets
    const int nblk = (E + CHUNK - 1) / CHUNK;// 391 scatter blocks
    const int nT32 = (N + 31) >> 5;          // 3125 layer tiles

    // Workspace (~60 MB)
    unsigned short* hbX = (unsigned short*)d_ws;             // N*64 bf16
    unsigned short* hbY = hbX + (size_t)N * 64;              // N*64 bf16
    int* bucketed2 = (int*)(hbY + (size_t)N * 64);           // nblk*CHUNK
    int* offsTab   = bucketed2 + (size_t)nblk * CHUNK;       // nblk*1025
    int* csrOut    = offsTab + (size_t)nblk * 1025;          // NB*CAP
    int* rowstart  = csrOut + (size_t)NB * CAP;              // N
    int* rowend    = rowstart + N;                           // N
    float* bnstats = (float*)(rowend + N);                   // 6*64
    float* partS   = bnstats + 384;                          // nT32*64
    float* partQ   = partS + (size_t)nT32 * 64;              // nT32*64
    unsigned short* w1T0 = (unsigned short*)(partQ + (size_t)nT32 * 64); // 64*32
    unsigned short* w1T  = w1T0 + 64 * 32;                   // 2*64*64
    unsigned short* w2T  = w1T + 2 * 64 * 64;                // 3*64*64

    const int* srcv = ei;
    const int* dstv = ei + E;

    // --- CSR build (+ fused weight prep in extra block) ---
    scatter_sort<<<nblk + 1, 512, 0, stream>>>(srcv, dstv, bucketed2, offsTab, E, nblk,
                                               w1_0, w1_r, w2, w1T0, w1T, w2T);
    bucket_csr<<<NB, 256, 0, stream>>>(bucketed2, offsTab, csrOut, rowstart, rowend, N, nblk);

    // --- Layer 0 (fused agg3 + MLP) ---
    gin_layer<true><<<nT32, 256, 0, stream>>>(x, rowstart, rowend, csrOut,
                                              nullptr, nullptr, nullptr, nullptr,
                                              (const uint4*)w1T0, b1,
                                              (const uint4*)w2T, b2,
                                              (uint4*)hbX, partS, partQ, N);
    bn_reduce<<<64, 256, 0, stream>>>(partS, partQ, bnstats, bnstats + 64, nT32);

    // --- Layer 1 (fused BN0+agg + MLP) ---
    gin_layer<false><<<nT32, 256, 0, stream>>>(hbX, rowstart, rowend, csrOut,
                                               bnstats, bnstats + 64, gamma, beta,
                                               (const uint4*)w1T, b1 + 64,
                                               (const uint4*)(w2T + 4096), b2 + 64,
                                               (uint4*)hbY, partS, partQ, N);
    bn_reduce<<<64, 256, 0, stream>>>(partS, partQ, bnstats + 128, bnstats + 192, nT32);

    // --- Layer 2 (fused BN1+agg + MLP) ---
    gin_layer<false><<<nT32, 256, 0, stream>>>(hbY, rowstart, rowend, csrOut,
                                               bnstats + 128, bnstats + 192,
                                               gamma + 64, beta + 64,
                                               (const uint4*)(w1T + 4096), b1 + 128,
                                               (const uint4*)(w2T + 8192), b2 + 128,
                                               (uint4*)hbX, partS, partQ, N);
    bn_reduce<<<64, 256, 0, stream>>>(partS, partQ, bnstats + 256, bnstats + 320, nT32);

    // --- BN2 apply + pool + output matmul ---
    bn_pool_out<<<512, 256, 0, stream>>>((const uint4*)hbX, batch,
                                         bnstats + 256, bnstats + 320,
                                         gamma + 128, beta + 128, wout, bout, out, N);
}

// Round 21
// 330.758 us; speedup vs baseline: 1.0533x; 1.0533x over previous
//
#include <hip/hip_runtime.h>

// GIN encoder: N=100k, E=3.2M, G=512, H=64, L=3.
// Round 21 = R19's gin_layer (unroll-4, VGPR 48, occ 42%) + R20's vectorized
// bn_pool_out + fused weight prep. R20's unroll-8 reverted (VGPR 68 ->
// occupancy 27% -> 68us; stated risk materialized).

#define NBMAX 1024
#define CAP 4608
#define CHUNK 8192
#define NBLK_MAX 512
#define MSTR 72   // LDS row stride in shorts (9 uint4, bank-staggered)

typedef __attribute__((ext_vector_type(8))) short bf16x8;
typedef __attribute__((ext_vector_type(4))) float f32x4;

static __device__ __forceinline__ bf16x8 as_bf16x8(uint4 u) {
    union { uint4 a; bf16x8 b; } x; x.a = u; return x.b;
}
static __device__ __forceinline__ unsigned short bf16r(float v) {
    unsigned u = __float_as_uint(v);
    return (unsigned short)((u + 0x7FFFu + ((u >> 16) & 1u)) >> 16);
}
static __device__ __forceinline__ unsigned bf16pack2(float a, float b) {
    return (unsigned)bf16r(a) | ((unsigned)bf16r(b) << 16);
}

// ---- scatter_sort + fused weight prep (block == nblk does weights) ----
__global__ __launch_bounds__(512) void scatter_sort(
    const int* __restrict__ src, const int* __restrict__ dst,
    int* __restrict__ bucketed2, int* __restrict__ offsTab, int E, int nblk,
    const float* __restrict__ w1_0, const float* __restrict__ w1_r,
    const float* __restrict__ w2, unsigned short* __restrict__ w1T0,
    unsigned short* __restrict__ w1T, unsigned short* __restrict__ w2T) {
    int t = threadIdx.x, blk = blockIdx.x;
    if (blk >= nblk) {
        for (int i = t; i < 64 * 32; i += 512) {
            int c = i >> 5, k = i & 31;
            w1T0[i] = bf16r(k < 3 ? w1_0[k * 64 + c] : 0.f);
        }
        for (int i = t; i < 2 * 64 * 64; i += 512) {
            int l = i >> 12, r = i & 4095, c = r >> 6, k = r & 63;
            w1T[i] = bf16r(w1_r[l * 4096 + k * 64 + c]);
        }
        for (int i = t; i < 3 * 64 * 64; i += 512) {
            int l = i >> 12, r = i & 4095, c = r >> 6, k = r & 63;
            w2T[i] = bf16r(w2[l * 4096 + k * 64 + c]);
        }
        return;
    }
    __shared__ int hist[NBMAX];
    __shared__ int offs[NBMAX];
    __shared__ int stage[CHUNK];
    __shared__ int wsum8[8];
    int e0 = blk * CHUNK, e1 = min(e0 + CHUNK, E);
    int len = e1 - e0;
    hist[t] = 0; hist[t + 512] = 0;
    __syncthreads();
    for (int e = e0 + t; e < e1; e += 512) atomicAdd(&hist[dst[e] >> 7], 1);
    __syncthreads();
    int h0 = hist[2 * t], h1 = hist[2 * t + 1];
    int pair = h0 + h1;
    int lane = t & 63;
    int incl = pair;
#pragma unroll
    for (int d = 1; d < 64; d <<= 1) {
        int up = __shfl_up(incl, d);
        if (lane >= d) incl += up;
    }
    if (lane == 63) wsum8[t >> 6] = incl;
    __syncthreads();
    int wid = t >> 6, wpre = 0;
    for (int i = 0; i < wid; i++) wpre += wsum8[i];
    int exclP = wpre + incl - pair;
    offs[2 * t] = exclP;
    offs[2 * t + 1] = exclP + h0;
    hist[2 * t] = 0; hist[2 * t + 1] = 0;
    __syncthreads();
    offsTab[blk * 1025 + t] = offs[t];
    offsTab[blk * 1025 + t + 512] = offs[t + 512];
    if (t == 0) offsTab[blk * 1025 + 1024] = len;
    for (int e = e0 + t; e < e1; e += 512) {
        int d = dst[e];
        int bk = d >> 7;
        int r = offs[bk] + atomicAdd(&hist[bk], 1);
        stage[r] = src[e] | ((d & 127) << 20);
    }
    __syncthreads();
    for (int j = t; j < len; j += 512) bucketed2[e0 + j] = stage[j];
}

// ---- bucket_csr v4: wave scans; binsearch run-gather; src-block then row
// counting sorts -> CSR with ~src-ascending rows ----
__global__ __launch_bounds__(256) void bucket_csr(
    const int* __restrict__ bucketed2, const int* __restrict__ offsTab,
    int* __restrict__ csrOut, int* __restrict__ rowstart, int* __restrict__ rowend,
    int N, int nblk) {
    __shared__ int ein[CAP];
    __shared__ int emid[CAP];
    __shared__ int runs[NBLK_MAX];
    __shared__ int rbeg[NBLK_MAX];
    __shared__ int hist[128];
    __shared__ int base[129];
    __shared__ int wsum4[4];
    __shared__ int wtot2[2];
    int b = blockIdx.x, t = threadIdx.x, node0 = b << 7;
    for (int r = t; r < NBLK_MAX; r += 256) {
        int l = 0, g0 = 0;
        if (r < nblk) {
            int beg = offsTab[r * 1025 + b];
            int end = offsTab[r * 1025 + b + 1];
            l = end - beg;
            g0 = r * CHUNK + beg;
        }
        runs[r] = l;
        rbeg[r] = g0;
    }
    __syncthreads();
    {
        int l0 = runs[2 * t], l1 = runs[2 * t + 1];
        int pair = l0 + l1;
        int lane = t & 63;
        int incl = pair;
#pragma unroll
        for (int d = 1; d < 64; d <<= 1) {
            int up = __shfl_up(incl, d);
            if (lane >= d) incl += up;
        }
        if (lane == 63) wsum4[t >> 6] = incl;
        __syncthreads();
        int wid = t >> 6, wpre = 0;
        for (int i = 0; i < wid; i++) wpre += wsum4[i];
        int exclP = wpre + incl - pair;
        runs[2 * t] = exclP + l0;
        runs[2 * t + 1] = exclP + l0 + l1;
    }
    __syncthreads();
    int cnt = min(runs[NBLK_MAX - 1], CAP);
    for (int j = t; j < cnt; j += 256) {
        int lo = 0, hi = nblk - 1;
        while (lo < hi) {
            int m = (lo + hi) >> 1;
            if (runs[m] > j) hi = m; else lo = m + 1;
        }
        int st = lo ? runs[lo - 1] : 0;
        ein[j] = bucketed2[rbeg[lo] + (j - st)];
    }
    if (t < 128) hist[t] = 0;
    __syncthreads();
    for (int j = t; j < cnt; j += 256) atomicAdd(&hist[(ein[j] & 0xFFFFF) >> 10], 1);
    __syncthreads();
    {
        int lane = t & 63;
        int hv = (t < 128) ? hist[t] : 0;
        int incl = hv;
#pragma unroll
        for (int d = 1; d < 64; d <<= 1) {
            int up = __shfl_up(incl, d);
            if (lane >= d) incl += up;
        }
        if (t < 128 && lane == 63) wtot2[t >> 6] = incl;
        __syncthreads();
        if (t >= 64 && t < 128) incl += wtot2[0];
        if (t < 128) { base[t + 1] = incl; hist[t] = 0; }
        if (t == 0) base[0] = 0;
    }
    __syncthreads();
    for (int j = t; j < cnt; j += 256) {
        int p = ein[j];
        int sb = (p & 0xFFFFF) >> 10;
        int pos = base[sb] + atomicAdd(&hist[sb], 1);
        emid[pos] = p;
    }
    __syncthreads();
    if (t < 128) hist[t] = 0;
    __syncthreads();
    for (int j = t; j < cnt; j += 256) atomicAdd(&hist[emid[j] >> 20], 1);
    __syncthreads();
    {
        int lane = t & 63;
        int hv = (t < 128) ? hist[t] : 0;
        int incl = hv;
#pragma unroll
        for (int d = 1; d < 64; d <<= 1) {
            int up = __shfl_up(incl, d);
            if (lane >= d) incl += up;
        }
        if (t < 128 && lane == 63) wtot2[t >> 6] = incl;
        __syncthreads();
        if (t >= 64 && t < 128) incl += wtot2[0];
        if (t < 128) { base[t + 1] = incl; hist[t] = 0; }
        if (t == 0) base[0] = 0;
    }
    __syncthreads();
    if (t < 128) {
        int n = node0 + t;
        if (n < N) {
            rowstart[n] = b * CAP + base[t];
            rowend[n] = b * CAP + base[t + 1];
        }
    }
    __syncthreads();
    for (int j = t; j < cnt; j += 256) {
        int p = emid[j];
        int local = p >> 20;
        int pos = base[local] + atomicAdd(&hist[local], 1);
        ein[pos] = p & 0xFFFFF;
    }
    __syncthreads();
    for (int j = t; j < cnt; j += 256) csrOut[b * CAP + j] = ein[j];
}

// bf16x2-packed accumulate of relu(v*sc+sh)
__device__ __forceinline__ void accum_bf16(const uint4 u,
                                           const float4 scA, const float4 scB,
                                           const float4 shA, const float4 shB,
                                           float* __restrict__ a) {
    a[0] += fmaxf(__uint_as_float(u.x << 16) * scA.x + shA.x, 0.f);
    a[1] += fmaxf(__uint_as_float(u.x & 0xFFFF0000u) * scA.y + shA.y, 0.f);
    a[2] += fmaxf(__uint_as_float(u.y << 16) * scA.z + shA.z, 0.f);
    a[3] += fmaxf(__uint_as_float(u.y & 0xFFFF0000u) * scA.w + shA.w, 0.f);
    a[4] += fmaxf(__uint_as_float(u.z << 16) * scB.x + shB.x, 0.f);
    a[5] += fmaxf(__uint_as_float(u.z & 0xFFFF0000u) * scB.y + shB.y, 0.f);
    a[6] += fmaxf(__uint_as_float(u.w << 16) * scB.z + shB.z, 0.f);
    a[7] += fmaxf(__uint_as_float(u.w & 0xFFFF0000u) * scB.w + shB.w, 0.f);
}

// ---- fused GIN layer v4.1 (R19 verified): 256 threads, 32-node tile ----
template <bool L0>
__global__ __launch_bounds__(256) void gin_layer(
    const void* __restrict__ actInRaw,
    const int* __restrict__ rowstart, const int* __restrict__ rowend,
    const int* __restrict__ csr,
    const float* __restrict__ bnsumPrev, const float* __restrict__ bnsqPrev,
    const float* __restrict__ gammaPrev, const float* __restrict__ betaPrev,
    const uint4* __restrict__ w1Tu, const float* __restrict__ b1,
    const uint4* __restrict__ w2Tu, const float* __restrict__ b2,
    uint4* __restrict__ houtU4,
    float* __restrict__ partS, float* __restrict__ partQ, int N) {
    __shared__ __align__(16) unsigned short acts[32 * MSTR];  // 4.5KB
    __shared__ __align__(16) unsigned short mids[32 * MSTR];  // 4.5KB
    __shared__ float red[8][64];                              // 2KB
    __shared__ float scs[64], shs[64];
    int t = threadIdx.x;
    int tileBase = blockIdx.x * 32;
    uint4* actsU4 = (uint4*)acts;
    const uint4* midU4 = (const uint4*)mids;
    const uint4 z4 = make_uint4(0, 0, 0, 0);

    if (!L0) {
        if (t < 64) {
            float mu = bnsumPrev[t] / (float)N;
            float var = bnsqPrev[t] / (float)N - mu * mu;
            float s = gammaPrev[t] * rsqrtf(var + 1e-5f);
            scs[t] = s;
            shs[t] = betaPrev[t] - mu * s;
        }
        __syncthreads();
    }

    // ---- gather phase ----
    if (L0) {
        const float* x = (const float*)actInRaw;
        int ni = t & 31, seg = t >> 5;
        int n = tileBase + ni;
        float s0 = 0.f, s1 = 0.f, s2 = 0.f;
        if (n < N) {
            int srow = rowstart[n], erow = rowend[n];
            for (int j = srow + seg; j < erow; j += 8) {
                int nb = csr[j];
                s0 += x[nb * 3]; s1 += x[nb * 3 + 1]; s2 += x[nb * 3 + 2];
            }
            if (seg == 0) { s0 += x[n * 3]; s1 += x[n * 3 + 1]; s2 += x[n * 3 + 2]; }
        }
        float* stg = (float*)mids;
        stg[seg * 96 + ni * 3 + 0] = s0;
        stg[seg * 96 + ni * 3 + 1] = s1;
        stg[seg * 96 + ni * 3 + 2] = s2;
        __syncthreads();
        if (t < 32) {
            float a0 = 0.f, a1 = 0.f, a2 = 0.f;
#pragma unroll
            for (int g2 = 0; g2 < 8; g2++) {
                a0 += stg[g2 * 96 + t * 3 + 0];
                a1 += stg[g2 * 96 + t * 3 + 1];
                a2 += stg[g2 * 96 + t * 3 + 2];
            }
            actsU4[t * 9] = make_uint4(bf16pack2(a0, a1), bf16pack2(a2, 0.f), 0u, 0u);
        }
    } else {
        const uint4* hr = (const uint4*)actInRaw;
        int ni = t >> 3, l = t & 7;
        int n = tileBase + ni;
        int c0i = l * 8;
        float4 scA = *(const float4*)&scs[c0i], scB = *(const float4*)&scs[c0i + 4];
        float4 shA = *(const float4*)&shs[c0i], shB = *(const float4*)&shs[c0i + 4];
        float A[8] = {0,0,0,0,0,0,0,0};
        float B[8] = {0,0,0,0,0,0,0,0};
        if (n < N) {
            accum_bf16(hr[(size_t)n * 8 + l], scA, scB, shA, shB, A);  // self
            int s = rowstart[n], e = rowend[n];
            int j = s;
            for (; j + 3 < e; j += 4) {
                int i0 = csr[j], i1 = csr[j + 1], i2 = csr[j + 2], i3 = csr[j + 3];
                uint4 w0 = hr[(size_t)i0 * 8 + l];
                uint4 w1 = hr[(size_t)i1 * 8 + l];
                uint4 w2 = hr[(size_t)i2 * 8 + l];
                uint4 w3 = hr[(size_t)i3 * 8 + l];
                accum_bf16(w0, scA, scB, shA, shB, A);
                accum_bf16(w1, scA, scB, shA, shB, B);
                accum_bf16(w2, scA, scB, shA, shB, A);
                accum_bf16(w3, scA, scB, shA, shB, B);
            }
            for (; j < e; j++) {
                uint4 w = hr[(size_t)csr[j] * 8 + l];
                accum_bf16(w, scA, scB, shA, shB, A);
            }
        }
        uint4 o;
        o.x = bf16pack2(A[0] + B[0], A[1] + B[1]);
        o.y = bf16pack2(A[2] + B[2], A[3] + B[3]);
        o.z = bf16pack2(A[4] + B[4], A[5] + B[5]);
        o.w = bf16pack2(A[6] + B[6], A[7] + B[7]);
        actsU4[ni * 9 + l] = o;
    }

    // ---- MFMA phase: wave w -> col-group w*16, row-groups 0..1 ----
    int w = t >> 6, l64 = t & 63, m16 = l64 & 15, q = l64 >> 4;
    int col = w * 16 + m16;
    bf16x8 w1f0, w1f1, w2f0, w2f1;
    float bias1 = b1[col], bias2 = b2[col];
    if (L0) {
        w1f0 = as_bf16x8(w1Tu[col * 4 + q]);
    } else {
        w1f0 = as_bf16x8(w1Tu[col * 8 + q]);
        w1f1 = as_bf16x8(w1Tu[col * 8 + 4 + q]);
    }
    w2f0 = as_bf16x8(w2Tu[col * 8 + q]);
    w2f1 = as_bf16x8(w2Tu[col * 8 + 4 + q]);
    __syncthreads();  // S1: acts ready
#pragma unroll
    for (int rg = 0; rg < 2; rg++) {
        int rloc = rg * 16 + m16;
        bf16x8 a0 = as_bf16x8(L0 ? (q == 0 ? actsU4[rloc * 9] : z4)
                                 : actsU4[rloc * 9 + q]);
        f32x4 acc = {bias1, bias1, bias1, bias1};
        if (L0) {
            acc = __builtin_amdgcn_mfma_f32_16x16x32_bf16(a0, w1f0, acc, 0, 0, 0);
        } else {
            bf16x8 a1 = as_bf16x8(actsU4[rloc * 9 + 4 + q]);
            acc = __builtin_amdgcn_mfma_f32_16x16x32_bf16(a0, w1f0, acc, 0, 0, 0);
            acc = __builtin_amdgcn_mfma_f32_16x16x32_bf16(a1, w1f1, acc, 0, 0, 0);
        }
#pragma unroll
        for (int r = 0; r < 4; r++) {
            int row = rg * 16 + q * 4 + r;
            mids[row * MSTR + col] = bf16r(fmaxf(acc[r], 0.f));
        }
    }
    __syncthreads();  // S2: mids ready
    f32x4 accs[2];
#pragma unroll
    for (int rg = 0; rg < 2; rg++) {
        int rloc = rg * 16 + m16;
        bf16x8 a20 = as_bf16x8(midU4[rloc * 9 + q]);
        bf16x8 a21 = as_bf16x8(midU4[rloc * 9 + 4 + q]);
        f32x4 acc = {bias2, bias2, bias2, bias2};
        acc = __builtin_amdgcn_mfma_f32_16x16x32_bf16(a20, w2f0, acc, 0, 0, 0);
        acc = __builtin_amdgcn_mfma_f32_16x16x32_bf16(a21, w2f1, acc, 0, 0, 0);
        accs[rg] = acc;
    }
    float sA = 0.f, sB = 0.f, qA = 0.f, qB = 0.f;
#pragma unroll
    for (int rg = 0; rg < 2; rg++) {
#pragma unroll
        for (int r = 0; r < 4; r++) {
            int row = rg * 16 + q * 4 + r;
            float v = accs[rg][r];
            if (tileBase + row < N) {
                if (rg == 0) { sA += v; qA += v * v; } else { sB += v; qB += v * v; }
            }
            acts[row * MSTR + col] = bf16r(v);
        }
    }
    __syncthreads();  // S3: output staged
    {
        int row = t >> 3, qo = t & 7;
        int gr = tileBase + row;
        if (gr < N) houtU4[(size_t)gr * 8 + qo] = actsU4[row * 9 + qo];
    }
    red[q][col] = sA;
    red[4 + q][col] = sB;
    __syncthreads();
    if (t < 64) {
        float S = 0.f;
        for (int i = 0; i < 8; i++) S += red[i][t];
        partS[blockIdx.x * 64 + t] = S;
    }
    __syncthreads();
    red[q][col] = qA;
    red[4 + q][col] = qB;
    __syncthreads();
    if (t < 64) {
        float S = 0.f;
        for (int i = 0; i < 8; i++) S += red[i][t];
        partQ[blockIdx.x * 64 + t] = S;
    }
}

// ---- bn_reduce v2: 64 blocks, block b reduces column b over nParts ----
__global__ __launch_bounds__(256) void bn_reduce(
    const float* __restrict__ partS, const float* __restrict__ partQ,
    float* __restrict__ bnsum, float* __restrict__ bnsq, int nParts) {
    __shared__ float rs[256], rq[256];
    int b = blockIdx.x, t = threadIdx.x;
    float S = 0.f, Q = 0.f;
    for (int p = t; p < nParts; p += 256) {
        S += partS[p * 64 + b];
        Q += partQ[p * 64 + b];
    }
    rs[t] = S; rq[t] = Q;
    __syncthreads();
    for (int off = 128; off > 0; off >>= 1) {
        if (t < off) { rs[t] += rs[t + off]; rq[t] += rq[t + off]; }
        __syncthreads();
    }
    if (t == 0) { bnsum[b] = rs[0]; bnsq[b] = rq[0]; }
}

// ---- BN apply + mean-pool + output matmul; vectorized uint4 reads ----
__device__ __forceinline__ int lowb(const int* __restrict__ a, int n, int v) {
    int lo = 0, hi = n;
    while (lo < hi) {
        int m = (lo + hi) >> 1;
        if (a[m] < v) lo = m + 1; else hi = m;
    }
    return lo;
}

__global__ __launch_bounds__(256) void bn_pool_out(
    const uint4* __restrict__ hr, const int* __restrict__ batch,
    const float* __restrict__ bnsum, const float* __restrict__ bnsq,
    const float* __restrict__ gamma, const float* __restrict__ beta,
    const float* __restrict__ wout, const float* __restrict__ bout,
    float* __restrict__ out, int N) {
    __shared__ float sc[64], sh[64];
    __shared__ float part[32][64];
    __shared__ float gr[64];
    __shared__ int range[2];
    int g = blockIdx.x, t = threadIdx.x;
    if (t < 64) {
        float mu = bnsum[t] / (float)N;
        float var = bnsq[t] / (float)N - mu * mu;
        float s = gamma[t] * rsqrtf(var + 1e-5f);
        sc[t] = s;
        sh[t] = beta[t] - mu * s;
    }
    if (t == 64) range[0] = lowb(batch, N, g);
    if (t == 65) range[1] = lowb(batch, N, g + 1);
    __syncthreads();
    int s0 = range[0], s1 = range[1];
    int o = t & 7, ro = t >> 3;
    int c0 = o * 8;
    float4 scA = *(const float4*)&sc[c0], scB = *(const float4*)&sc[c0 + 4];
    float4 shA = *(const float4*)&sh[c0], shB = *(const float4*)&sh[c0 + 4];
    float A[8] = {0,0,0,0,0,0,0,0};
    for (int n = s0 + ro; n < s1; n += 32) {
        uint4 u = hr[(size_t)n * 8 + o];
        accum_bf16(u, scA, scB, shA, shB, A);
    }
#pragma unroll
    for (int k = 0; k < 8; k++) part[ro][c0 + k] = A[k];
    __syncthreads();
    if (t < 64) {
        float S = 0.f;
        for (int i = 0; i < 32; i++) S += part[i][t];
        float c = (float)(s1 - s0);
        gr[t] = (c > 0.f) ? S / c : 0.f;
    }
    __syncthreads();
    if (t < 64) {
        float a = bout[t];
        for (int f = 0; f < 64; f++) a += gr[f] * wout[f * 64 + t];
        out[g * 64 + t] = a;
    }
}

extern "C" void kernel_launch(void* const* d_in, const int* in_sizes, int n_in,
                              void* d_out, int out_size, void* d_ws, size_t ws_size,
                              hipStream_t stream) {
    const float* x     = (const float*)d_in[0];
    const int*   ei    = (const int*)d_in[1];
    const int*   batch = (const int*)d_in[2];
    const float* w1_0  = (const float*)d_in[3];
    const float* w1_r  = (const float*)d_in[4];
    const float* b1    = (const float*)d_in[5];
    const float* w2    = (const float*)d_in[6];
    const float* b2    = (const float*)d_in[7];
    const float* gamma = (const float*)d_in[8];
    const float* beta  = (const float*)d_in[9];
    const float* wout  = (const float*)d_in[10];
    const float* bout  = (const float*)d_in[11];
    float* out = (float*)d_out;

    const int N = in_sizes[2];               // 100000
    const int E = in_sizes[1] / 2;           // 3200000
    const int NB = (N + 127) >> 7;           // 782 buckets
    const int nblk = (E + CHUNK - 1) / CHUNK;// 391 scatter blocks
    const int nT32 = (N + 31) >> 5;          // 3125 layer tiles

    // Workspace (~60 MB)
    unsigned short* hbX = (unsigned short*)d_ws;             // N*64 bf16
    unsigned short* hbY = hbX + (size_t)N * 64;              // N*64 bf16
    int* bucketed2 = (int*)(hbY + (size_t)N * 64);           // nblk*CHUNK
    int* offsTab   = bucketed2 + (size_t)nblk * CHUNK;       // nblk*1025
    int* csrOut    = offsTab + (size_t)nblk * 1025;          // NB*CAP
    int* rowstart  = csrOut + (size_t)NB * CAP;              // N
    int* rowend    = rowstart + N;                           // N
    float* bnstats = (float*)(rowend + N);                   // 6*64
    float* partS   = bnstats + 384;                          // nT32*64
    float* partQ   = partS + (size_t)nT32 * 64;              // nT32*64
    unsigned short* w1T0 = (unsigned short*)(partQ + (size_t)nT32 * 64); // 64*32
    unsigned short* w1T  = w1T0 + 64 * 32;                   // 2*64*64
    unsigned short* w2T  = w1T + 2 * 64 * 64;                // 3*64*64

    const int* srcv = ei;
    const int* dstv = ei + E;

    // --- CSR build (+ fused weight prep in extra block) ---
    scatter_sort<<<nblk + 1, 512, 0, stream>>>(srcv, dstv, bucketed2, offsTab, E, nblk,
                                               w1_0, w1_r, w2, w1T0, w1T, w2T);
    bucket_csr<<<NB, 256, 0, stream>>>(bucketed2, offsTab, csrOut, rowstart, rowend, N, nblk);

    // --- Layer 0 (fused agg3 + MLP) ---
    gin_layer<true><<<nT32, 256, 0, stream>>>(x, rowstart, rowend, csrOut,
                                              nullptr, nullptr, nullptr, nullptr,
                                              (const uint4*)w1T0, b1,
                                              (const uint4*)w2T, b2,
                                              (uint4*)hbX, partS, partQ, N);
    bn_reduce<<<64, 256, 0, stream>>>(partS, partQ, bnstats, bnstats + 64, nT32);

    // --- Layer 1 (fused BN0+agg + MLP) ---
    gin_layer<false><<<nT32, 256, 0, stream>>>(hbX, rowstart, rowend, csrOut,
                                               bnstats, bnstats + 64, gamma, beta,
                                               (const uint4*)w1T, b1 + 64,
                                               (const uint4*)(w2T + 4096), b2 + 64,
                                               (uint4*)hbY, partS, partQ, N);
    bn_reduce<<<64, 256, 0, stream>>>(partS, partQ, bnstats + 128, bnstats + 192, nT32);

    // --- Layer 2 (fused BN1+agg + MLP) ---
    gin_layer<false><<<nT32, 256, 0, stream>>>(hbY, rowstart, rowend, csrOut,
                                               bnstats + 128, bnstats + 192,
                                               gamma + 64, beta + 64,
                                               (const uint4*)(w1T + 4096), b1 + 128,
                                               (const uint4*)(w2T + 8192), b2 + 128,
                                               (uint4*)hbX, partS, partQ, N);
    bn_reduce<<<64, 256, 0, stream>>>(partS, partQ, bnstats + 256, bnstats + 320, nT32);

    // --- BN2 apply + pool + output matmul ---
    bn_pool_out<<<512, 256, 0, stream>>>((const uint4*)hbX, batch,
                                         bnstats + 256, bnstats + 320,
                                         gamma + 128, beta + 128, wout, bout, out, N);
}